// Round 7
// baseline (242.845 us; speedup 1.0000x reference)
//
#include <hip/hip_runtime.h>
#include <cstdint>
#include <cstddef>

#define NROWS 100000
#define FIN 512
#define HIDDEN 256
#define NCLS 50
#define PF 4  // A-prefetch ring depth (power of 2)

typedef __attribute__((ext_vector_type(8))) short s16x8;
typedef __attribute__((ext_vector_type(4))) float f32x4;

__device__ __forceinline__ unsigned short f2bf(float f) {
  unsigned int u = __float_as_uint(f);
  u += 0x7fffu + ((u >> 16) & 1u);
  return (unsigned short)(u >> 16);
}

// packed fp32x2 -> bf16x2 (RNE), single VALU op
__device__ __forceinline__ unsigned int cvt_pk_bf16(float lo, float hi) {
  unsigned int r;
  asm("v_cvt_pk_bf16_f32 %0, %1, %2" : "=v"(r) : "v"(lo), "v"(hi));
  return r;
}

__device__ __forceinline__ f32x4 mfma_bf16(s16x8 a, s16x8 b, f32x4 c) {
  return __builtin_amdgcn_mfma_f32_16x16x32_bf16(a, b, c, 0, 0, 0);
}

// prep:
//  w1tb[(k>>3)*2048 + c*8 + (k&7)] = bf16(W1[k][c])   (k<512, c<256) -> 256KB
//     (each K-step of 32 k's = 4 kc-blocks = one contiguous 16KB span)
//  w2tb[(k>>3)*512  + c*8 + (k&7)] = bf16(W2[k][c]), c>=50 -> 0  (64 cols) 32KB
__global__ __launch_bounds__(256) void prep_kernel(
    const float* __restrict__ W1, const float* __restrict__ W2,
    unsigned short* __restrict__ w1tb, unsigned short* __restrict__ w2tb) {
  __shared__ float tile[64][65];
  const int b = blockIdx.x, t = threadIdx.x;
  if (b < 32) {
    const int k0 = (b >> 2) * 64, n0 = (b & 3) * 64;
    const int rq = t >> 6, col = t & 63;
#pragma unroll
    for (int i = 0; i < 16; ++i) {
      int row = i * 4 + rq;
      tile[row][col] = W1[(size_t)(k0 + row) * HIDDEN + n0 + col];
    }
    __syncthreads();
#pragma unroll
    for (int i = 0; i < 16; ++i) {
      int n = i * 4 + rq;
      const int k = k0 + col, c = n0 + n;
      w1tb[(size_t)(k >> 3) * 2048 + c * 8 + (k & 7)] = f2bf(tile[col][n]);
    }
  } else {
    const int b2i = b - 32;
#pragma unroll
    for (int i = 0; i < 16; ++i) {
      int idx = t + i * 256;
      int c = idx >> 6;
      int k = b2i * 64 + (idx & 63);
      float v = (c < NCLS) ? W2[(size_t)k * NCLS + c] : 0.0f;
      w2tb[(size_t)(k >> 3) * 512 + c * 8 + (k & 7)] = f2bf(v);
    }
  }
}

// Fused: out = log_softmax(relu(x@W1+b1) @ W2 + b2)
// 256 thr / 4 waves; EACH WAVE independently owns 16 rows x all 256 cols.
// NO __syncthreads anywhere. A-frags: per-lane global fp32 (ring, depth 4) ->
// cvt_pk bf16. B-frags: per-lane global from w1tb (16KB contiguous per K-step,
// L1-resident). GEMM2: h transposed through wave-PRIVATE 8KB LDS slice
// (XOR-mixed, conflict-free; intra-wave ordering via lgkmcnt only), B-frags
// from w2tb (32KB, L1-hot).
__global__ __launch_bounds__(256) void fused_kernel(
    const float* __restrict__ x, const unsigned short* __restrict__ w1tb,
    const unsigned short* __restrict__ w2tb, const float* __restrict__ b1,
    const float* __restrict__ b2, float* __restrict__ out) {
  __shared__ char smem[32768];  // 4 waves x 8KB private h slice

  const int t = threadIdx.x;
  const int lane = t & 63, wid = t >> 6;
  const int q = lane & 15, half = lane >> 4;
  const int rowbase = (blockIdx.x * 4 + wid) * 16;

  int rowq = rowbase + q;
  if (rowq > NROWS - 1) rowq = NROWS - 1;
  const float* const xrow = x + (size_t)rowq * FIN + half * 8;
  // per-lane invariant part of B address (elements)
  const unsigned short* const bq = w1tb + half * 2048 + q * 8;

  f32x4 acc[16];
#pragma unroll
  for (int n = 0; n < 16; ++n) acc[n] = (f32x4){0.f, 0.f, 0.f, 0.f};

  // A-prefetch ring
  float4 ra[PF][2];
#pragma unroll
  for (int s = 0; s < PF; ++s) {
    ra[s][0] = *(const float4*)(xrow + s * 32);
    ra[s][1] = *(const float4*)(xrow + s * 32 + 4);
  }

#pragma unroll
  for (int ks = 0; ks < 16; ++ks) {
    const int sl = ks & (PF - 1);
    union { unsigned int u[4]; s16x8 v; } cv;
    cv.u[0] = cvt_pk_bf16(ra[sl][0].x, ra[sl][0].y);
    cv.u[1] = cvt_pk_bf16(ra[sl][0].z, ra[sl][0].w);
    cv.u[2] = cvt_pk_bf16(ra[sl][1].x, ra[sl][1].y);
    cv.u[3] = cvt_pk_bf16(ra[sl][1].z, ra[sl][1].w);
    const s16x8 af = cv.v;
    if (ks + PF < 16) {
      ra[sl][0] = *(const float4*)(xrow + (ks + PF) * 32);
      ra[sl][1] = *(const float4*)(xrow + (ks + PF) * 32 + 4);
    }
    const unsigned short* bp = bq + ks * 8192;  // this step's 16KB B-block
#pragma unroll
    for (int n = 0; n < 16; ++n) {
      s16x8 bf = *(const s16x8*)(bp + n * 128);
      acc[n] = mfma_bf16(af, bf, acc[n]);
    }
  }

  // ---- h (16x256) -> wave-private LDS, bias+relu+bf16, XOR-mix layout ----
  // elem (rl, col) at rl*256 + ((ch ^ mix(rl))<<3) + (col&7), ch = col>>3,
  // mix(rl) = (rl&7) ^ ((rl>>3)<<1)  -> writes/reads spread over all 32 banks.
  unsigned short* const hw = (unsigned short*)(smem + wid * 8192);
#pragma unroll
  for (int n = 0; n < 16; ++n) {
    const int col = n * 16 + q;
    const float bias = b1[col];
    const int ch = col >> 3, b7 = col & 7;
#pragma unroll
    for (int r = 0; r < 4; ++r) {
      const int rl = half * 4 + r;
      const int mix = (rl & 7) ^ ((rl >> 3) << 1);
      float v = fmaxf(acc[n][r] + bias, 0.0f);
      hw[rl * 256 + ((ch ^ mix) << 3) + b7] = f2bf(v);
    }
  }
  asm volatile("s_waitcnt lgkmcnt(0)" ::: "memory");
  __builtin_amdgcn_sched_barrier(0);

  // ---- GEMM2: z(16x64) = h @ w2tb^T (K=256), per-wave, B from global ----
  f32x4 acc2[4];
#pragma unroll
  for (int n = 0; n < 4; ++n) acc2[n] = (f32x4){0.f, 0.f, 0.f, 0.f};
  const int mixq = (q & 7) ^ ((q >> 3) << 1);
  const unsigned short* const wq = w2tb + half * 512 + q * 8;
#pragma unroll
  for (int ksub = 0; ksub < 8; ++ksub) {
    const int kch = ksub * 4 + half;
    s16x8 a2 = *(const s16x8*)(hw + q * 256 + ((kch ^ mixq) << 3));
#pragma unroll
    for (int n = 0; n < 4; ++n) {
      s16x8 bf = *(const s16x8*)(wq + ksub * 2048 + n * 128);
      acc2[n] = mfma_bf16(a2, bf, acc2[n]);
    }
  }

  float bias2[4];
#pragma unroll
  for (int n = 0; n < 4; ++n) {
    const int c = n * 16 + q;
    bias2[n] = (c < NCLS) ? b2[c] : 0.0f;
  }
#pragma unroll
  for (int r = 0; r < 4; ++r) {
    float vals[4];
    float mx = -1e30f;
#pragma unroll
    for (int n = 0; n < 4; ++n) {
      const int c = n * 16 + q;
      float v = acc2[n][r] + bias2[n];
      vals[n] = v;
      if (c < NCLS) mx = fmaxf(mx, v);
    }
    for (int off = 8; off >= 1; off >>= 1)
      mx = fmaxf(mx, __shfl_xor(mx, off, 64));
    float s = 0.f;
#pragma unroll
    for (int n = 0; n < 4; ++n) {
      const int c = n * 16 + q;
      if (c < NCLS) s += __expf(vals[n] - mx);
    }
    for (int off = 8; off >= 1; off >>= 1) s += __shfl_xor(s, off, 64);
    const float lz = __logf(s);
    const int rowg = rowbase + half * 4 + r;
    if (rowg < NROWS) {
#pragma unroll
      for (int n = 0; n < 4; ++n) {
        const int c = n * 16 + q;
        if (c < NCLS) out[(size_t)rowg * NCLS + c] = vals[n] - mx - lz;
      }
    }
  }
}

extern "C" void kernel_launch(void* const* d_in, const int* in_sizes, int n_in,
                              void* d_out, int out_size, void* d_ws, size_t ws_size,
                              hipStream_t stream) {
  const float* x  = (const float*)d_in[0];
  // d_in[1] = edge_index: dead (ALPHA==1.0 makes APPNP the identity)
  const float* W1 = (const float*)d_in[2];
  const float* b1 = (const float*)d_in[3];
  const float* W2 = (const float*)d_in[4];
  const float* b2 = (const float*)d_in[5];
  float* out = (float*)d_out;

  char* ws = (char*)d_ws;
  unsigned short* w1tb = (unsigned short*)(ws);           // 256 KB
  unsigned short* w2tb = (unsigned short*)(ws + 262144);  // 32 KB

  prep_kernel<<<36, 256, 0, stream>>>(W1, W2, w1tb, w2tb);
  fused_kernel<<<(NROWS + 63) / 64, 256, 0, stream>>>(x, w1tb, w2tb, b1, b2, out);
}

// Round 8
// 64.491 us; speedup vs baseline: 3.7656x; 3.7656x over previous
//
#include <hip/hip_runtime.h>
#include <cstdint>
#include <cstddef>

#define NROWS 100000
#define FIN 512
#define HIDDEN 256
#define NCLS 50

typedef __attribute__((ext_vector_type(8))) short s16x8;
typedef __attribute__((ext_vector_type(4))) float f32x4;

// round-to-nearest-even fp32->bf16 (scalar)
__device__ __forceinline__ unsigned short f2bf(float f) {
  unsigned int u = __float_as_uint(f);
  u += 0x7fffu + ((u >> 16) & 1u);
  return (unsigned short)(u >> 16);
}

// packed fp32x2 -> bf16x2 (RNE) - single VALU op
__device__ __forceinline__ unsigned int cvt_pk_bf16(float lo, float hi) {
  unsigned int r;
  asm("v_cvt_pk_bf16_f32 %0, %1, %2" : "=v"(r) : "v"(lo), "v"(hi));
  return r;
}

__device__ __forceinline__ void gload_lds16(const void* g, void* l) {
  __builtin_amdgcn_global_load_lds(
      (const __attribute__((address_space(1))) void*)g,
      (__attribute__((address_space(3))) void*)l, 16, 0, 0);
}

__device__ __forceinline__ f32x4 mfma_bf16(s16x8 a, s16x8 b, f32x4 c) {
  return __builtin_amdgcn_mfma_f32_16x16x32_bf16(a, b, c, 0, 0, 0);
}

// prep: w1t[n][k] = bf16(W1[k][n])  [256][512]   (blocks 0..31, LDS transpose)
//       w2t[c][k] = bf16(W2[k][c]), c>=50 -> 0   [64][256]   (blocks 32..35)
__global__ __launch_bounds__(256) void prep_kernel(
    const float* __restrict__ W1, const float* __restrict__ W2,
    unsigned short* __restrict__ w1t, unsigned short* __restrict__ w2t) {
  __shared__ float tile[64][65];
  const int b = blockIdx.x, t = threadIdx.x;
  if (b < 32) {
    const int k0 = (b >> 2) * 64, n0 = (b & 3) * 64;
    const int rq = t >> 6, col = t & 63;
#pragma unroll
    for (int i = 0; i < 16; ++i) {
      int row = i * 4 + rq;
      tile[row][col] = W1[(size_t)(k0 + row) * HIDDEN + n0 + col];
    }
    __syncthreads();
#pragma unroll
    for (int i = 0; i < 16; ++i) {
      int n = i * 4 + rq;
      w1t[(size_t)(n0 + n) * FIN + k0 + col] = f2bf(tile[col][n]);
    }
  } else {
    const int b2i = b - 32;  // 0..3, k-range
#pragma unroll
    for (int i = 0; i < 16; ++i) {
      int idx = t + i * 256;          // 0..4095
      int c = idx >> 6;               // 0..63
      int k = b2i * 64 + (idx & 63);  // 0..255
      float v = (c < NCLS) ? W2[(size_t)k * NCLS + c] : 0.0f;
      w2t[(size_t)c * HIDDEN + k] = f2bf(v);
    }
  }
}

// Fused: out = log_softmax(relu(x@W1+b1) @ W2 + b2)
// 512 threads / 8 waves, tile 128 rows x 256 cols, BK=32.
// SWAPPED operand order: mfma(A=w1-frag, B=x-frag) -> lane holds 4 CONSECUTIVE
// h-cols at fixed x-row (D: col=lane&15 -> xrow, row=4*(lane>>4)+r -> hcol).
// Epilogue h-write: 16x b64 (cvt_pk pairs) instead of 64x scalar b16 ->
// bank conflicts eliminated (additive slot swizzle, 2-way max).
// A: x fp32 via global_load_lds (pre-swizzled source), dbuf 2x16KB.
// B: w1t bf16 via global_load_lds, dbuf 2x16KB.  Total LDS 64KB.
__global__ __launch_bounds__(512, 4) void fused_kernel(
    const float* __restrict__ x, const unsigned short* __restrict__ w1t,
    const unsigned short* __restrict__ w2t, const float* __restrict__ b1,
    const float* __restrict__ b2, float* __restrict__ out) {
  __shared__ char smem[65536];
  float* const Abase = (float*)smem;                              // 2 x 16KB fp32
  unsigned short* const Bbase = (unsigned short*)(smem + 32768);  // 2 x 16KB bf16

  const int t = threadIdx.x;
  const int lane = t & 63, wid = t >> 6;
  const int q = lane & 15, half = lane >> 4;
  const int wr = wid >> 1, wc = wid & 1;
  const int bm = blockIdx.x;

  // ---- staging: A tile [128 rows][32 f32] = 1024 chunks(16B), 2/thread ----
  // lds chunk (row,s) holds global chunk s^(row&7)  (128B-window permute)
  auto stage_A = [&](float* buf, int k0) {
#pragma unroll
    for (int i = 0; i < 2; ++i) {
      int c = t + i * 512;
      int row = c >> 3, s = c & 7;
      int grow = bm * 128 + row;
      if (grow > NROWS - 1) grow = NROWS - 1;
      gload_lds16(x + (size_t)grow * FIN + k0 + ((s ^ (row & 7)) << 2),
                  buf + c * 4);
    }
  };
  // ---- B tile [256 cols][32 bf16] = 1024 chunks, 2/thread ----
  // lds chunk (col,s) holds global chunk s^((col>>2)&3)  (64B-window permute)
  auto stage_B = [&](unsigned short* buf, int k0) {
#pragma unroll
    for (int i = 0; i < 2; ++i) {
      int c = t + i * 512;
      int col = c >> 2, s = c & 3;
      gload_lds16(w1t + (size_t)col * FIN + k0 + ((s ^ ((col >> 2) & 3)) << 3),
                  buf + c * 8);
    }
  };

  // acc[i][j]: i = hcol frag (8 of 16 cols), j = xrow frag (2 of 16 rows)
  // lane(q,half) reg r = h[xrow = (wr&1)*32 + j*16 + q][hcol = wc*128+i*16+4*half+r]
  f32x4 acc[8][2];
  const f32x4 z4 = {0.f, 0.f, 0.f, 0.f};
#pragma unroll
  for (int i = 0; i < 8; ++i)
#pragma unroll
    for (int j = 0; j < 2; ++j) acc[i][j] = z4;

  stage_A(Abase, 0);
  stage_B(Bbase, 0);
  __syncthreads();

  for (int ks = 0; ks < 16; ++ks) {
    const int cur = ks & 1;
    float* Ac = Abase + cur * 4096;
    unsigned short* Bc = Bbase + cur * 8192;
    if (ks < 15) {
      stage_A(Abase + (cur ^ 1) * 4096, (ks + 1) * 32);
      stage_B(Bbase + (cur ^ 1) * 8192, (ks + 1) * 32);
    }

    // x fragments (now the B-operand; same reads as before)
    s16x8 af[2];
#pragma unroll
    for (int m = 0; m < 2; ++m) {
      const int row = wr * 32 + m * 16 + q;
      const int cb = row * 8;
      f32x4 lo = *(const f32x4*)(Ac + (cb + ((half * 2) ^ (q & 7))) * 4);
      f32x4 hi = *(const f32x4*)(Ac + (cb + ((half * 2 + 1) ^ (q & 7))) * 4);
      union { unsigned int u[4]; s16x8 v; } cvu;
      cvu.u[0] = cvt_pk_bf16(lo[0], lo[1]);
      cvu.u[1] = cvt_pk_bf16(lo[2], lo[3]);
      cvu.u[2] = cvt_pk_bf16(hi[0], hi[1]);
      cvu.u[3] = cvt_pk_bf16(hi[2], hi[3]);
      af[m] = cvu.v;
    }

#pragma unroll
    for (int n = 0; n < 8; ++n) {
      const int col = wc * 128 + n * 16 + q;
      s16x8 bf = *(const s16x8*)(Bc + col * 32 + ((half ^ ((q >> 2) & 3)) << 3));
      // swapped: w1-frag is the A operand -> D[hcol][xrow]
      acc[n][0] = mfma_bf16(bf, af[0], acc[n][0]);
      acc[n][1] = mfma_bf16(bf, af[1], acc[n][1]);
    }
    __syncthreads();
  }

  // ================= epilogue =================
  unsigned short* const hls = (unsigned short*)smem;   // [64][256] bf16, 32KB
  unsigned short* const wls = Bbase;                   // [64][256] bf16, 32KB
  const int p_of_wave = wid >> 2;  // waves 0-3 own rows 0-63, 4-7 own 64-127

  // stage w2t once (all threads): lds chunk (row,s) holds global chunk s^(row&7)
#pragma unroll
  for (int i = 0; i < 4; ++i) {
    int c = t + i * 512;
    int row = c >> 5, s = c & 31;
    gload_lds16(w2t + (size_t)row * HIDDEN + ((s ^ (row & 7)) << 3), wls + c * 8);
  }

  // h-write: lane holds 4 consecutive hcols at fixed local row rl ->
  // two cvt_pk + one b64 store. Layout: element (rl, hcol) lives at
  // rl*256 + slot*8 + (hcol&7), slot = ((hcol>>3) + rl) & 31  (additive swz).
  auto write_h = [&]() {
#pragma unroll
    for (int i = 0; i < 8; ++i) {
      const int hc0 = wc * 128 + i * 16 + half * 4;  // hcol base (r=0..3)
      const float4 b4 = *(const float4*)(b1 + hc0);
      const int ch = hc0 >> 3;                       // 16wc + 2i + (half>>1)
#pragma unroll
      for (int j = 0; j < 2; ++j) {
        const int rl = (wr & 1) * 32 + j * 16 + q;   // local row 0..63
        const float v0 = fmaxf(acc[i][j][0] + b4.x, 0.0f);
        const float v1 = fmaxf(acc[i][j][1] + b4.y, 0.0f);
        const float v2 = fmaxf(acc[i][j][2] + b4.z, 0.0f);
        const float v3 = fmaxf(acc[i][j][3] + b4.w, 0.0f);
        uint2 u;
        u.x = cvt_pk_bf16(v0, v1);
        u.y = cvt_pk_bf16(v2, v3);
        const int slot = (ch + rl) & 31;
        *(uint2*)(hls + rl * 256 + slot * 8 + (half & 1) * 4) = u;
      }
    }
  };

  // GEMM2 pass over 64 rows by 4 waves (aw = wid&3): 16 rows x 64 cols each
  auto gemm2_pass = [&](int p) {
    f32x4 acc2[4];
#pragma unroll
    for (int n = 0; n < 4; ++n) acc2[n] = z4;
    const int arl = (wid & 3) * 16 + q;
#pragma unroll
    for (int ks = 0; ks < HIDDEN; ks += 32) {
      const int g = (ks >> 3) + half;  // k-chunk index
      s16x8 a2 = *(const s16x8*)(hls + arl * 256 + (((g + arl) & 31) << 3));
#pragma unroll
      for (int n = 0; n < 4; ++n) {
        const int c = n * 16 + q;
        s16x8 b2f = *(const s16x8*)(wls + c * 256 + ((g ^ (c & 7)) << 3));
        acc2[n] = mfma_bf16(a2, b2f, acc2[n]);
      }
    }
    float bias2[4];
#pragma unroll
    for (int n = 0; n < 4; ++n) {
      const int c = n * 16 + q;
      bias2[n] = (c < NCLS) ? b2[c] : 0.0f;
    }
#pragma unroll
    for (int r = 0; r < 4; ++r) {
      float vals[4];
      float mx = -1e30f;
#pragma unroll
      for (int n = 0; n < 4; ++n) {
        const int c = n * 16 + q;
        float v = acc2[n][r] + bias2[n];
        vals[n] = v;
        if (c < NCLS) mx = fmaxf(mx, v);
      }
      for (int off = 8; off >= 1; off >>= 1)
        mx = fmaxf(mx, __shfl_xor(mx, off, 64));
      float s = 0.f;
#pragma unroll
      for (int n = 0; n < 4; ++n) {
        const int c = n * 16 + q;
        if (c < NCLS) s += __expf(vals[n] - mx);
      }
      for (int off = 8; off >= 1; off >>= 1) s += __shfl_xor(s, off, 64);
      const float lz = __logf(s);
      const int rowg = bm * 128 + p * 64 + (wid & 3) * 16 + half * 4 + r;
      if (rowg < NROWS) {
#pragma unroll
        for (int n = 0; n < 4; ++n) {
          const int c = n * 16 + q;
          if (c < NCLS) out[(size_t)rowg * NCLS + c] = vals[n] - mx - lz;
        }
      }
    }
  };

  if (p_of_wave == 0) write_h();   // h rows 0..63
  __syncthreads();                 // drains w2t glds + h writes
  if (p_of_wave == 0) gemm2_pass(0);
  __syncthreads();                 // pass-0 reads done
  if (p_of_wave == 1) write_h();   // h rows 64..127 overwrite hls
  __syncthreads();
  if (p_of_wave == 1) gemm2_pass(1);
}

extern "C" void kernel_launch(void* const* d_in, const int* in_sizes, int n_in,
                              void* d_out, int out_size, void* d_ws, size_t ws_size,
                              hipStream_t stream) {
  const float* x  = (const float*)d_in[0];
  // d_in[1] = edge_index: dead (ALPHA==1.0 makes APPNP the identity)
  const float* W1 = (const float*)d_in[2];
  const float* b1 = (const float*)d_in[3];
  const float* W2 = (const float*)d_in[4];
  const float* b2 = (const float*)d_in[5];
  float* out = (float*)d_out;

  char* ws = (char*)d_ws;
  unsigned short* w1t = (unsigned short*)(ws);           // 256 KB
  unsigned short* w2t = (unsigned short*)(ws + 262144);  // 32 KB

  prep_kernel<<<36, 256, 0, stream>>>(W1, W2, w1t, w2t);
  fused_kernel<<<(NROWS + 127) / 128, 512, 0, stream>>>(x, w1t, w2t, b1, b2, out);
}